// Round 5
// baseline (560.433 us; speedup 1.0000x reference)
//
#include <hip/hip_runtime.h>
#include <stdint.h>

// ---------------------------------------------------------------------------
// Fused causal attention (B=4, S=4096, D=1024, single head), fp32 in/out.
// Round 5: TLP-oriented core. 128x256 tile, BK=32, 8 waves, 72 KiB LDS
// (3 slots -> 2-K-tile prefetch runway), 2 blocks/CU, minimal sync:
// one counted-vmcnt + one barrier per K-tile; compiler schedules ds_read/MFMA.
// Balance: scores triangle flattened; pv split-K for heavy q-tiles + combine.
// ---------------------------------------------------------------------------

#define DM   1024
#define SEQ  4096
#define NB   4
#define MTOT (NB * SEQ)

#define SLOT_U16 12288   // 24 KiB per slot: A 128x32 (4096 u16) + B 256x32 (8192 u16)
#define LDS_U16  36864   // 3 slots = 72 KiB

typedef unsigned short u16;
typedef unsigned int u32;
typedef __bf16 bf16x8 __attribute__((ext_vector_type(8)));
typedef float f32x4 __attribute__((ext_vector_type(4)));

__device__ __forceinline__ u16 f2bf(float f) {
    u32 u = __float_as_uint(f);
    u32 r = (u + 0x7fffu + ((u >> 16) & 1u)) >> 16; // RNE
    return (u16)r;
}

__device__ __forceinline__ void gl_lds16(const void* gptr, void* lptr) {
    __builtin_amdgcn_global_load_lds(
        (const __attribute__((address_space(1))) void*)gptr,
        (__attribute__((address_space(3))) void*)lptr,
        16, 0, 0);
}

// --------------------------- converts --------------------------------------
__global__ void cvt_kernel(const float* __restrict__ in, u16* __restrict__ out, int n8) {
    int i = blockIdx.x * 256 + threadIdx.x;
    if (i >= n8) return;
    const float4* p = (const float4*)in + (size_t)i * 2;
    float4 a = p[0], b = p[1];
    uint4 o;
    o.x = (u32)f2bf(a.x) | ((u32)f2bf(a.y) << 16);
    o.y = (u32)f2bf(a.z) | ((u32)f2bf(a.w) << 16);
    o.z = (u32)f2bf(b.x) | ((u32)f2bf(b.y) << 16);
    o.w = (u32)f2bf(b.z) | ((u32)f2bf(b.w) << 16);
    ((uint4*)out)[i] = o;
}

__global__ void zero_kernel(float* __restrict__ p, int n) {
    int i = blockIdx.x * 256 + threadIdx.x;
    if (i < n) p[i] = 0.f;
}

// --------------------------- 128x256 BK=32 GEMM core ------------------------
// NT GEMM: A [.][lda], B [.][ldb] bf16 row-major (K contiguous).
// 512 threads = 8 waves (2M x 4N), per-wave 64x64 output (acc[4][4]).
// LDS rows are 64 B; swizzle key (row&3)<<4 (2-way bank aliasing = free).
// gl_lds dest strictly linear (byte = tid*16 within each region); swizzle is
// applied by inverse-permuting the global source column (same involution as
// the ds_read side).
__device__ __forceinline__ void stage_tile(const u16* __restrict__ A, int lda, int m0,
                                           const u16* __restrict__ B, int ldb, int n0,
                                           int kt, u16* slot, int tid) {
    int row  = tid >> 2;                    // 0..127
    int csrc = (((tid & 3) ^ (row & 3)) << 3); // inverse-swizzled src elem col
    gl_lds16(A + (size_t)(m0 + row) * lda + kt * 32 + csrc,       slot + tid * 8);
    gl_lds16(B + (size_t)(n0 + row) * ldb + kt * 32 + csrc,       slot + 4096 + tid * 8);
    gl_lds16(B + (size_t)(n0 + 128 + row) * ldb + kt * 32 + csrc, slot + 8192 + tid * 8);
}

__device__ __forceinline__ void gemm128x256(const u16* __restrict__ A, int lda,
                                            const u16* __restrict__ B, int ldb,
                                            int m0, int n0, int NT,
                                            u16* lds, f32x4 acc[4][4]) {
    const int tid  = threadIdx.x;
    const int lane = tid & 63;
    const int w    = tid >> 6;
    const int wr   = w >> 2, wc = w & 3;   // wave tile rows wr*64, cols wc*64
    const int gi   = lane >> 4, fr = lane & 15;
    const int cx   = (gi * 16) ^ ((fr & 3) << 4); // swizzled byte col in 64B row
    const int rA   = wr * 64 + fr;
    const int rB   = wc * 64 + fr;

    u16 *sc = lds, *sn1 = lds + SLOT_U16, *sn2 = lds + 2 * SLOT_U16;

    // prologue: tiles 0 and 1 staged (3 loads/thread each)
    stage_tile(A, lda, m0, B, ldb, n0, 0, sc, tid);
    if (NT > 1) stage_tile(A, lda, m0, B, ldb, n0, 1, sn1, tid);
    asm volatile("s_waitcnt vmcnt(3)" ::: "memory"); // tile0 landed (tile1 in flight)
    __builtin_amdgcn_sched_barrier(0);
    __builtin_amdgcn_s_barrier();

    for (int t = 0; t < NT; ++t) {
        // prefetch tile t+2 into the free slot (runway ~2 K-tiles)
        if (t + 2 < NT) stage_tile(A, lda, m0, B, ldb, n0, t + 2, sn2, tid);

        const char* sb = (const char*)sc;
        bf16x8 af[4], bq[4];
#pragma unroll
        for (int mi = 0; mi < 4; ++mi)
            af[mi] = *(const bf16x8*)(sb + (rA + mi * 16) * 64 + cx);
#pragma unroll
        for (int ni = 0; ni < 4; ++ni)
            bq[ni] = *(const bf16x8*)(sb + 8192 + (rB + ni * 16) * 64 + cx);
#pragma unroll
        for (int mi = 0; mi < 4; ++mi)
#pragma unroll
            for (int ni = 0; ni < 4; ++ni)
                acc[mi][ni] = __builtin_amdgcn_mfma_f32_16x16x32_bf16(
                    af[mi], bq[ni], acc[mi][ni], 0, 0, 0);

        if (t + 1 < NT) {
            // wait tile t+1 landed (leave t+2's 3 loads in flight), then fence
            if (t + 2 < NT) { asm volatile("s_waitcnt vmcnt(3)" ::: "memory"); }
            else            { asm volatile("s_waitcnt vmcnt(0)" ::: "memory"); }
            __builtin_amdgcn_sched_barrier(0);
            __builtin_amdgcn_s_barrier();
        }
        u16* tmp = sc; sc = sn1; sn1 = sn2; sn2 = tmp; // rotate (no indexed array)
    }
}

#define ACC_INIT(acc)                                                        \
    _Pragma("unroll") for (int a_ = 0; a_ < 4; ++a_)                         \
    _Pragma("unroll") for (int b_ = 0; b_ < 4; ++b_)                         \
        acc[a_][b_] = f32x4{0.f, 0.f, 0.f, 0.f};

// --------------------------- stage A: QKV projection ------------------------
__global__ __launch_bounds__(512, 2) void qkv_kernel(
    const u16* __restrict__ xb,
    const u16* __restrict__ wq, const u16* __restrict__ wk, const u16* __restrict__ wv,
    u16* __restrict__ Q, u16* __restrict__ K, u16* __restrict__ Vt)
{
    __shared__ __align__(16) u16 lds[LDS_U16];
    const int nt = blockIdx.x;      // 0..3 (256-wide)
    const int mt = blockIdx.y;      // 0..127 (128-row)
    const int which = blockIdx.z;   // 0:Q 1:K 2:V
    const u16* W = which == 0 ? wq : which == 1 ? wk : wv;

    f32x4 acc[4][4];
    ACC_INIT(acc);
    gemm128x256(xb, DM, W, DM, mt * 128, nt * 256, DM / 32, lds, acc);

    const int lane = threadIdx.x & 63;
    const int w = threadIdx.x >> 6, wr = w >> 2, wc = w & 3;
    const int gi = lane >> 4, fr = lane & 15;

    if (which < 2) {
        u16* O = which == 0 ? Q : K;
#pragma unroll
        for (int mi = 0; mi < 4; ++mi)
#pragma unroll
            for (int ni = 0; ni < 4; ++ni)
#pragma unroll
                for (int i = 0; i < 4; ++i) {
                    int gm = mt * 128 + wr * 64 + mi * 16 + gi * 4 + i;
                    int gn = nt * 256 + wc * 64 + ni * 16 + fr;
                    O[(size_t)gm * DM + gn] = f2bf(acc[mi][ni][i]);
                }
    } else {
        // Vt[b][e][s]; register quad contiguous in s -> 8B stores.
#pragma unroll
        for (int mi = 0; mi < 4; ++mi)
#pragma unroll
            for (int ni = 0; ni < 4; ++ni) {
                int gm = mt * 128 + wr * 64 + mi * 16 + gi * 4;
                int gn = nt * 256 + wc * 64 + ni * 16 + fr;
                int b = gm >> 12, s = gm & (SEQ - 1);
                uint2 pk;
                pk.x = (u32)f2bf(acc[mi][ni][0]) | ((u32)f2bf(acc[mi][ni][1]) << 16);
                pk.y = (u32)f2bf(acc[mi][ni][2]) | ((u32)f2bf(acc[mi][ni][3]) << 16);
                *(uint2*)(Vt + ((size_t)(b * DM + gn)) * SEQ + s) = pk;
            }
    }
}

// --------------------------- stage B: scores + exp + rowsum -----------------
// Flattened causal triangle: 272 (qi,kt) tiles per batch, no ghost blocks.
__global__ __launch_bounds__(512, 2) void scores_kernel(
    const u16* __restrict__ Q, const u16* __restrict__ K,
    u16* __restrict__ P, float* __restrict__ rowsum, int b0)
{
    int rem = blockIdx.x, qi = 0;
    while (rem >= (qi >> 1) + 1) { rem -= (qi >> 1) + 1; qi++; }
    const int kt = rem;             // 0..floor(qi/2)
    const int z = blockIdx.z;
    const int b = b0 + z;
    const u16* Qb = Q + (size_t)b * SEQ * DM;
    const u16* Kb = K + (size_t)b * SEQ * DM;
    u16* Pb = P + (size_t)z * SEQ * SEQ;

    __shared__ __align__(16) u16 lds[LDS_U16];
    f32x4 acc[4][4];
    ACC_INIT(acc);
    gemm128x256(Qb, DM, Kb, DM, qi * 128, kt * 256, DM / 32, lds, acc);

    const int lane = threadIdx.x & 63;
    const int w = threadIdx.x >> 6, wr = w >> 2, wc = w & 3;
    const int gi = lane >> 4, fr = lane & 15;
    const int qt0 = qi * 128, kt0 = kt * 256;

#pragma unroll
    for (int mi = 0; mi < 4; ++mi) {
        float rs[4] = {0.f, 0.f, 0.f, 0.f};
#pragma unroll
        for (int ni = 0; ni < 4; ++ni)
#pragma unroll
            for (int i = 0; i < 4; ++i) {
                int gq = qt0 + wr * 64 + mi * 16 + gi * 4 + i;
                int gk = kt0 + wc * 64 + ni * 16 + fr;
                float p = (gk <= gq) ? __expf(acc[mi][ni][i] * 0.03125f) : 0.f;
                Pb[(size_t)gq * SEQ + gk] = f2bf(p);
                rs[i] += p;
            }
#pragma unroll
        for (int i = 0; i < 4; ++i) {
            float s = rs[i];
            s += __shfl_xor(s, 1);
            s += __shfl_xor(s, 2);
            s += __shfl_xor(s, 4);
            s += __shfl_xor(s, 8); // sum across the 16-lane fr group
            if (fr == 0) {
                int gq = qt0 + wr * 64 + mi * 16 + gi * 4 + i;
                atomicAdd(&rowsum[(size_t)b * SEQ + gq], s);
            }
        }
    }
}

// --------------------------- stage C: PV (+split-K) -------------------------
// Item table (split mode), sorted big-first. val = qi | half<<8 | split<<9.
#define PVI(qi, h, s) ((u16)((qi) | ((h) << 8) | ((s) << 9)))
__device__ const u16 pv_items[48] = {
    PVI(15,0,0), PVI(31,0,1), PVI(31,1,1),
    PVI(30,0,1), PVI(30,1,1),
    PVI(14,0,0), PVI(29,0,1), PVI(29,1,1),
    PVI(28,0,1), PVI(28,1,1),
    PVI(13,0,0), PVI(27,0,1), PVI(27,1,1),
    PVI(26,0,1), PVI(26,1,1),
    PVI(12,0,0), PVI(25,0,1), PVI(25,1,1),
    PVI(24,0,1), PVI(24,1,1),
    PVI(11,0,0), PVI(23,0,1), PVI(23,1,1),
    PVI(22,0,1), PVI(22,1,1),
    PVI(10,0,0), PVI(21,0,1), PVI(21,1,1),
    PVI(20,0,1), PVI(20,1,1),
    PVI( 9,0,0), PVI(19,0,1), PVI(19,1,1),
    PVI(18,0,1), PVI(18,1,1),
    PVI( 8,0,0), PVI(17,0,1), PVI(17,1,1),
    PVI(16,0,1), PVI(16,1,1),
    PVI( 7,0,0), PVI( 6,0,0), PVI( 5,0,0), PVI( 4,0,0),
    PVI( 3,0,0), PVI( 2,0,0), PVI( 1,0,0), PVI( 0,0,0)
};

__global__ __launch_bounds__(512, 2) void pv_kernel(
    const u16* __restrict__ P, const u16* __restrict__ Vt,
    const float* __restrict__ rowsum, float* __restrict__ out,
    float* __restrict__ part, int b0, int gshift, int mode)
{
    const int x = blockIdx.x;
    const int item = x >> gshift;
    const int z = x & ((1 << gshift) - 1);
    const int et = blockIdx.y;      // 0..3 (256-wide e-tile)
    int qi, half, split;
    if (mode) { u16 v = pv_items[item]; qi = v & 255 & 63; half = (v >> 8) & 1; split = (v >> 9) & 1; }
    else      { qi = 31 - item; half = 0; split = 0; }
    const int b = b0 + z;
    const u16* Pb = P + (size_t)z * SEQ * SEQ;
    const u16* Vb = Vt + (size_t)b * DM * SEQ;

    int NT;
    size_t koff;
    if (split) { NT = 2 * (qi + 1); koff = (size_t)(half ? 2 * (qi + 1) : 0) * 32; }
    else       { NT = 4 * (qi + 1); koff = 0; }

    __shared__ __align__(16) u16 lds[LDS_U16];
    f32x4 acc[4][4];
    ACC_INIT(acc);
    gemm128x256(Pb + koff, SEQ, Vb + koff, SEQ, qi * 128, et * 256, NT, lds, acc);

    const int lane = threadIdx.x & 63;
    const int w = threadIdx.x >> 6, wr = w >> 2, wc = w & 3;
    const int gi = lane >> 4, fr = lane & 15;

#pragma unroll
    for (int mi = 0; mi < 4; ++mi)
#pragma unroll
        for (int i = 0; i < 4; ++i) {
            int gq = qi * 128 + wr * 64 + mi * 16 + gi * 4 + i;
#pragma unroll
            for (int ni = 0; ni < 4; ++ni) {
                int ge = et * 256 + wc * 64 + ni * 16 + fr;
                float v = acc[mi][ni][i];
                if (!split) {
                    float inv = 1.0f / rowsum[(size_t)b * SEQ + gq];
                    out[((size_t)b * SEQ + gq) * DM + ge] = v * inv;
                } else if (half == 0) {
                    out[((size_t)b * SEQ + gq) * DM + ge] = v;           // raw
                } else {
                    part[((size_t)b * 2048 + (gq - 2048)) * DM + ge] = v; // raw
                }
            }
        }
}

// --------------------------- combine (split rows only) ----------------------
__global__ void combine_kernel(float* __restrict__ out, const float* __restrict__ part,
                               const float* __restrict__ rowsum) {
    int i = blockIdx.x * 256 + threadIdx.x;       // float4 idx: 4b x 2048r x 256
    int e4 = i & 255;
    int r  = (i >> 8) & 2047;
    int b  = i >> 19;
    int gq = r + 2048;
    float inv = 1.0f / rowsum[(size_t)b * SEQ + gq];
    size_t oi = ((size_t)b * SEQ + gq) * 256 + e4;
    size_t pi = ((size_t)b * 2048 + r) * 256 + e4;
    float4 o = ((const float4*)out)[oi];
    float4 p = ((const float4*)part)[pi];
    float4 rlt;
    rlt.x = (o.x + p.x) * inv;
    rlt.y = (o.y + p.y) * inv;
    rlt.z = (o.z + p.z) * inv;
    rlt.w = (o.w + p.w) * inv;
    ((float4*)out)[oi] = rlt;
}

// --------------------------- launch ----------------------------------------
extern "C" void kernel_launch(void* const* d_in, const int* in_sizes, int n_in,
                              void* d_out, int out_size, void* d_ws, size_t ws_size,
                              hipStream_t stream)
{
    const float* x  = (const float*)d_in[0];
    const float* wq = (const float*)d_in[1];
    const float* wk = (const float*)d_in[2];
    const float* wv = (const float*)d_in[3];
    // d_in[4] = causal mask (tril ones) — implemented analytically, not read.
    float* out = (float*)d_out;
    char* ws = (char*)d_ws;
    const size_t MB = 1u << 20;

    // need(g, split): P(32g) + Q/K/Vt(96) + weights(6) + [part 32] + rowsum + slack
    auto need = [&](int g, int split) {
        return (size_t)(32 * g + 96 + 6 + (split ? 32 : 0)) * MB
               + (size_t)(NB * SEQ * 4) + 65536;
    };
    int g, do_split;
    if      (ws_size >= need(4, 1)) { g = 4; do_split = 1; }
    else if (ws_size >= need(2, 1)) { g = 2; do_split = 1; }
    else if (ws_size >= need(1, 1)) { g = 1; do_split = 1; }
    else if (ws_size >= need(4, 0)) { g = 4; do_split = 0; }
    else if (ws_size >= need(2, 0)) { g = 2; do_split = 0; }
    else                            { g = 1; do_split = 0; }
    const int gshift = (g == 4) ? 2 : (g == 2) ? 1 : 0;

    size_t off = 0;
    u16* P  = (u16*)(ws);            off += (size_t)32 * MB * g;
    u16* xb = (u16*)(ws);            // aliases P: x_bf16 dead before P written
    u16* Q  = (u16*)(ws + off);      off += 32 * MB;
    u16* K  = (u16*)(ws + off);      off += 32 * MB;
    u16* Vt = (u16*)(ws + off);      off += 32 * MB;
    u16* wqb = (u16*)(ws + off);     off += 2 * MB;
    u16* wkb = (u16*)(ws + off);     off += 2 * MB;
    u16* wvb = (u16*)(ws + off);     off += 2 * MB;
    float* part = (float*)(ws + off); if (do_split) off += 32 * MB;
    float* rowsum = (float*)(ws + off);

    cvt_kernel<<<(MTOT * DM / 8) / 256, 256, 0, stream>>>(x, xb, MTOT * DM / 8);
    cvt_kernel<<<(DM * DM / 8) / 256, 256, 0, stream>>>(wq, wqb, DM * DM / 8);
    cvt_kernel<<<(DM * DM / 8) / 256, 256, 0, stream>>>(wk, wkb, DM * DM / 8);
    cvt_kernel<<<(DM * DM / 8) / 256, 256, 0, stream>>>(wv, wvb, DM * DM / 8);
    zero_kernel<<<(NB * SEQ) / 256, 256, 0, stream>>>(rowsum, NB * SEQ);

    qkv_kernel<<<dim3(4, 128, 3), 512, 0, stream>>>(xb, wqb, wkb, wvb, Q, K, Vt);

    const int nitems = do_split ? 48 : 32;
    for (int b0 = 0; b0 < NB; b0 += g) {
        scores_kernel<<<dim3(272, 1, g), 512, 0, stream>>>(Q, K, P, rowsum, b0);
        pv_kernel<<<dim3(nitems * g, 4, 1), 512, 0, stream>>>(
            P, Vt, rowsum, out, part, b0, gshift, do_split);
    }
    if (do_split)
        combine_kernel<<<8192, 256, 0, stream>>>(out, part, rowsum);
}